// Round 3
// baseline (740.838 us; speedup 1.0000x reference)
//
#include <hip/hip_runtime.h>
#include <hip/hip_bf16.h>
#include <stdint.h>

typedef __bf16 bf16_t;
typedef __bf16 bf16x8 __attribute__((ext_vector_type(8)));
typedef __bf16 bf16x4_t __attribute__((ext_vector_type(4)));
typedef float f32x4 __attribute__((ext_vector_type(4)));

#define AS1 __attribute__((address_space(1)))
#define AS3 __attribute__((address_space(3)))

__device__ __forceinline__ void stage16(const void* g, void* l) {
    __builtin_amdgcn_global_load_lds((const AS1 uint32_t*)g, (AS3 uint32_t*)l, 16, 0, 0);
}

// C[M][N] = A[M][K](ld lda, bf16) * Bt[N][K]^T(bf16) + bias[N](fp32); OutT out, fp32 accum.
// BM=BN=128, BK=32, 256 threads = 4 waves (2x2), mfma_f32_16x16x32_bf16,
// global_load_lds width=16 staging, XOR chunk swizzle (2-way bank aliasing = free).
template <typename OutT>
__global__ __launch_bounds__(256, 2) void gemm_bt_bias(
    const bf16_t* __restrict__ A, int lda,
    const bf16_t* __restrict__ Bt,
    const float* __restrict__ bias,
    OutT* __restrict__ C, int ldc,
    int M, int N, int K)
{
    __shared__ char smem[16384];   // A tile [0,8192), B tile [8192,16384)
    const int tid  = threadIdx.x;
    const int wave = tid >> 6;
    const int lane = tid & 63;
    const int quad = lane >> 4;
    const int mrow = lane & 15;
    const int warpM = wave >> 1;
    const int warpN = wave & 1;
    const int mBase = blockIdx.y * 128;
    const int nBase = blockIdx.x * 128;

    f32x4 acc[4][4];
    const f32x4 fzero = {0.f, 0.f, 0.f, 0.f};
#pragma unroll
    for (int i = 0; i < 4; ++i)
#pragma unroll
        for (int j = 0; j < 4; ++j) acc[i][j] = fzero;

    // Staging: 512 chunks (16B) per tile, 256 threads -> 2 rounds per tile.
    // slot = r*256+tid; m = slot>>2; global chunk j = (slot&3) ^ ((m>>1)&3).
    const int s0 = tid, s1 = 256 + tid;
    const int am0 = s0 >> 2, aj0 = (s0 & 3) ^ ((am0 >> 1) & 3);
    const int am1 = s1 >> 2, aj1 = (s1 & 3) ^ ((am1 >> 1) & 3);
    const bf16_t* aS0 = A  + (size_t)(mBase + am0) * lda + aj0 * 8;
    const bf16_t* aS1 = A  + (size_t)(mBase + am1) * lda + aj1 * 8;
    const bf16_t* bS0 = Bt + (size_t)(nBase + am0) * K + aj0 * 8;
    const bf16_t* bS1 = Bt + (size_t)(nBase + am1) * K + aj1 * 8;
    char* const aD0 = smem + wave * 1024;           // lane i lands at +i*16
    char* const aD1 = smem + 4096  + wave * 1024;
    char* const bD0 = smem + 8192  + wave * 1024;
    char* const bD1 = smem + 12288 + wave * 1024;

    int aOff[4], bOff[4];
#pragma unroll
    for (int i = 0; i < 4; ++i) {
        int m = warpM * 64 + i * 16 + mrow;
        aOff[i] = (m * 4 + (quad ^ ((m >> 1) & 3))) * 16;
        int n = warpN * 64 + i * 16 + mrow;
        bOff[i] = 8192 + (n * 4 + (quad ^ ((n >> 1) & 3))) * 16;
    }

    for (int kt = 0; kt < K; kt += 32) {
        stage16(aS0 + kt, aD0);
        stage16(aS1 + kt, aD1);
        stage16(bS0 + kt, bD0);
        stage16(bS1 + kt, bD1);
        __syncthreads();
        bf16x8 af[4], bfv[4];
#pragma unroll
        for (int i = 0; i < 4; ++i) af[i]  = *(const bf16x8*)(smem + aOff[i]);
#pragma unroll
        for (int j = 0; j < 4; ++j) bfv[j] = *(const bf16x8*)(smem + bOff[j]);
#pragma unroll
        for (int i = 0; i < 4; ++i)
#pragma unroll
            for (int j = 0; j < 4; ++j)
                acc[i][j] = __builtin_amdgcn_mfma_f32_16x16x32_bf16(af[i], bfv[j], acc[i][j], 0, 0, 0);
        __syncthreads();
    }

    // D layout: col = lane&15, row = quad*4 + reg (m89-verified).
#pragma unroll
    for (int j = 0; j < 4; ++j) {
        const int col = nBase + warpN * 64 + j * 16 + mrow;
        const float bv = bias[col];
#pragma unroll
        for (int i = 0; i < 4; ++i) {
            const int row = mBase + warpM * 64 + i * 16 + quad * 4;
#pragma unroll
            for (int r = 0; r < 4; ++r)
                C[(size_t)(row + r) * ldc + col] = (OutT)(acc[i][j][r] + bv);
        }
    }
}

// fp32 -> bf16 elementwise, 4 elems/thread.
__global__ __launch_bounds__(256) void f32_to_bf16(const float* __restrict__ src,
                                                   bf16_t* __restrict__ dst, int n4) {
    int i = blockIdx.x * 256 + threadIdx.x;
    if (i >= n4) return;
    float4 v = ((const float4*)src)[i];
    bf16x4_t o;
    o.x = (bf16_t)v.x; o.y = (bf16_t)v.y; o.z = (bf16_t)v.z; o.w = (bf16_t)v.w;
    ((bf16x4_t*)dst)[i] = o;
}

// dst[cols][rows] (bf16) = src[rows][cols]^T (fp32), 64x64 LDS tiles (+1 pad col).
__global__ __launch_bounds__(256) void transpose_convert(
    const float* __restrict__ src, bf16_t* __restrict__ dst,
    int rows, int cols)
{
    __shared__ bf16_t t[64][65];
    const int tx = threadIdx.x & 63;
    const int ty = threadIdx.x >> 6;
    const int c0 = blockIdx.x * 64;
    const int r0 = blockIdx.y * 64;
#pragma unroll
    for (int r = ty; r < 64; r += 4)
        t[r][tx] = (bf16_t)src[(size_t)(r0 + r) * cols + c0 + tx];
    __syncthreads();
#pragma unroll
    for (int r = ty; r < 64; r += 4)
        dst[(size_t)(c0 + r) * rows + r0 + tx] = t[tx][r];
}

__global__ void concat_bias(const float* __restrict__ bq, const float* __restrict__ bk,
                            const float* __restrict__ bv, float* __restrict__ o) {
    int i = blockIdx.x * 256 + threadIdx.x;
    if (i >= 3072) return;
    o[i] = (i < 2048) ? bq[i] : (i < 2560 ? bk[i - 2048] : bv[i - 2560]);
}

// Per-token grouped attention (softmax over G=4 groups at same position), bf16 in/out.
// One block/token; wave w -> heads 4w..4w+3; lane holds elems 2*lane, 2*lane+1.
// Safe to write out in-place over q (wave reads its q head before writing it).
__global__ __launch_bounds__(256) void gqa_attn(
    const bf16_t* __restrict__ q, int sq,
    const bf16_t* __restrict__ kv, int skv,
    bf16_t* __restrict__ out, int so)
{
    const int token = blockIdx.x;
    const int wave = threadIdx.x >> 6, lane = threadIdx.x & 63;
    const bf16_t* qb  = q  + (size_t)token * sq;
    const bf16_t* kvb = kv + (size_t)token * skv;
    const float scale = 0.08838834764831845f;  // 1/sqrt(128)
    float k0[4], k1[4], v0[4], v1[4];
#pragma unroll
    for (int g = 0; g < 4; ++g) {
        uint32_t ku = *(const uint32_t*)(kvb + g * 128 + lane * 2);
        k0[g] = __uint_as_float(ku << 16);
        k1[g] = __uint_as_float(ku & 0xffff0000u);
        uint32_t vu = *(const uint32_t*)(kvb + 512 + g * 128 + lane * 2);
        v0[g] = __uint_as_float(vu << 16);
        v1[g] = __uint_as_float(vu & 0xffff0000u);
    }
#pragma unroll
    for (int hh = 0; hh < 4; ++hh) {
        const int h = wave * 4 + hh;
        uint32_t qu = *(const uint32_t*)(qb + h * 128 + lane * 2);
        float q0 = __uint_as_float(qu << 16);
        float q1 = __uint_as_float(qu & 0xffff0000u);
        float s[4];
#pragma unroll
        for (int g = 0; g < 4; ++g) s[g] = q0 * k0[g] + q1 * k1[g];
#pragma unroll
        for (int off = 32; off > 0; off >>= 1)
#pragma unroll
            for (int g = 0; g < 4; ++g) s[g] += __shfl_xor(s[g], off);
        float mx = fmaxf(fmaxf(s[0], s[1]), fmaxf(s[2], s[3]));
        float e[4], sum = 0.f;
#pragma unroll
        for (int g = 0; g < 4; ++g) { e[g] = __expf((s[g] - mx) * scale); sum += e[g]; }
        const float rs = 1.0f / sum;
        float o0 = 0.f, o1 = 0.f;
#pragma unroll
        for (int g = 0; g < 4; ++g) { o0 += e[g] * v0[g]; o1 += e[g] * v1[g]; }
        o0 *= rs; o1 *= rs;
        bf16_t* op = out + (size_t)token * so + h * 128 + lane * 2;
        op[0] = (bf16_t)o0;
        op[1] = (bf16_t)o1;
    }
}

// Copy q-region (ld 3072) -> compact [16384][2048], 8 bf16 (16B) per thread.
__global__ __launch_bounds__(256) void compact_q(const bf16_t* __restrict__ src,
                                                 bf16_t* __restrict__ dst) {
    size_t i = (size_t)blockIdx.x * 256 + threadIdx.x;  // 16384*256 threads
    size_t t = i >> 8;
    size_t c = (i & 255) * 8;
    *(uint4*)(dst + t * 2048 + c) = *(const uint4*)(src + t * 3072 + c);
}

extern "C" void kernel_launch(void* const* d_in, const int* in_sizes, int n_in,
                              void* d_out, int out_size, void* d_ws, size_t ws_size,
                              hipStream_t stream) {
    const float* hs = (const float*)d_in[0];
    const float* Wq = (const float*)d_in[1];
    const float* bq = (const float*)d_in[2];
    const float* Wk = (const float*)d_in[3];
    const float* bk = (const float*)d_in[4];
    const float* Wv = (const float*)d_in[5];
    const float* bv = (const float*)d_in[6];
    const float* Wo = (const float*)d_in[7];
    const float* bo = (const float*)d_in[8];
    float* outp = (float*)d_out;
    char* ws = (char*)d_ws;

    // ws layout (88.1 MB total):
    //   Wt   [3072][2048] bf16 : 0          .. 12,582,912
    //   Wot  [2048][2048] bf16 : 12,582,912 .. 20,971,520
    //   bqkv [3072]       f32  : 20,971,520 .. 20,983,808
    //   X    (67,108,864 B)    : 20,983,808 .. 88,092,672   (hs_bf16, then atto)
    bf16_t* Wt     = (bf16_t*)(ws);
    bf16_t* Wot    = (bf16_t*)(ws + 12582912);
    float*  bqkv   = (float*)(ws + 20971520);
    bf16_t* hs_b   = (bf16_t*)(ws + 20983808);
    bf16_t* atto   = (bf16_t*)(ws + 20983808);
    // qkv bf16 [16384][3072] = 100.7 MB lives in d_out (134.2 MB fp32) as scratch.
    bf16_t* qkv    = (bf16_t*)d_out;

    // Convert + transpose weights, concat biases, convert activations.
    f32_to_bf16<<<32768, 256, 0, stream>>>(hs, hs_b, 8388608);          // 16384*2048/4
    transpose_convert<<<dim3(32, 32), 256, 0, stream>>>(Wq, Wt, 2048, 2048);
    transpose_convert<<<dim3(8, 32), 256, 0, stream>>>(Wk, Wt + (size_t)2048 * 2048, 2048, 512);
    transpose_convert<<<dim3(8, 32), 256, 0, stream>>>(Wv, Wt + (size_t)2560 * 2048, 2048, 512);
    transpose_convert<<<dim3(32, 32), 256, 0, stream>>>(Wo, Wot, 2048, 2048);
    concat_bias<<<12, 256, 0, stream>>>(bq, bk, bv, bqkv);

    // QKV projection: [16384,2048] x [2048,3072] -> qkv (bf16, in d_out scratch)
    gemm_bt_bias<bf16_t><<<dim3(24, 128), 256, 0, stream>>>(
        hs_b, 2048, Wt, bqkv, qkv, 3072, 16384, 3072, 2048);
    // Grouped attention, in-place over q region of qkv
    gqa_attn<<<16384, 256, 0, stream>>>(qkv, 3072, qkv + 2048, 3072, qkv, 3072);
    // Move atto out of d_out (overlaying dead hs_b), then output projection -> fp32 d_out
    compact_q<<<16384, 256, 0, stream>>>(qkv, atto);
    gemm_bt_bias<float><<<dim3(16, 128), 256, 0, stream>>>(
        atto, 2048, Wot, bo, outp, 2048, 16384, 2048, 2048);
}